// Round 2
// baseline (23521.404 us; speedup 1.0000x reference)
//
#include <hip/hip_runtime.h>
#include <hip/hip_bf16.h>

#define D_   512
#define HID_ 2048
#define NH_  8
#define DH_  64
#define L_   6
#define B_   8
#define S_   512
#define T_   512
#define M_   4096            // B_*S_ rows
#define MD_  (M_ * D_)       // 2,097,152 floats per activation buffer

__device__ __forceinline__ float bf2f(unsigned short u) {
    union { unsigned int i; float f; } x; x.i = ((unsigned int)u) << 16; return x.f;
}

// Dual-dtype param loads: mode==1 -> storage is float32, mode==0 -> bf16 (ushort).
__device__ __forceinline__ float ldp(const void* p, size_t i, int mode) {
    return mode ? ((const float*)p)[i] : bf2f(((const unsigned short*)p)[i]);
}
__device__ __forceinline__ float4 ldp4(const void* p, size_t i, int mode) {
    if (mode) return *reinterpret_cast<const float4*>((const float*)p + i);
    short4 v = *reinterpret_cast<const short4*>((const unsigned short*)p + i);
    return make_float4(bf2f((unsigned short)v.x), bf2f((unsigned short)v.y),
                       bf2f((unsigned short)v.z), bf2f((unsigned short)v.w));
}

// ---------------- dtype probe ----------------
// Samples ushorts [512, 2560) of emi (rows >=1, i.e. non-PAD weights).
// bf16 storage: all |bf16(u)| <= ~0.1, essentially no exact zeros.
// f32 storage (full mantissa): even-index ushorts are f32 mantissa-low halves ->
//   decode as huge/NaN bf16 values.
// f32 storage (bf16-rounded values): even-index ushorts are all exactly 0.
__global__ __launch_bounds__(256) void detect_kernel(const void* em, int* flagp) {
    __shared__ int big, zc;
    if (threadIdx.x == 0) { big = 0; zc = 0; }
    __syncthreads();
    const unsigned short* u = (const unsigned short*)em;
    int lbig = 0, lzc = 0;
    for (int i = threadIdx.x; i < 2048; i += 256) {
        unsigned short x = u[512 + i];
        float v = bf2f(x);
        if (!(fabsf(v) < 1000.0f)) lbig = 1;          // huge / inf / NaN
        if ((((512 + i) & 1) == 0) && ((x & 0x7fff) == 0)) lzc++;
    }
    if (lbig) atomicOr(&big, 1);
    atomicAdd(&zc, lzc);
    __syncthreads();
    if (threadIdx.x == 0) flagp[0] = (big || zc >= 1000) ? 1 : 0;
}

// ---------------- embedding + positional encoding ----------------
__global__ __launch_bounds__(256) void embed_pe_kernel(const int* __restrict__ tok,
        const void* __restrict__ em, float* __restrict__ out, const int* __restrict__ flagp)
{
    const int mode = flagp[0];
    int idx = blockIdx.x * 256 + threadIdx.x;   // over M_*D_
    int d   = idx & (D_ - 1);
    int row = idx >> 9;                          // D_=512
    int s   = row & (S_ - 1);                    // S_=T_=512
    int t   = tok[row];
    float e = ldp(em, (size_t)t * D_ + d, mode);
    int d2  = d & ~1;
    float div = expf((float)d2 * (-9.210340371976184f / (float)D_));
    float a   = (float)s * div;
    float pe  = (d & 1) ? cosf(a) : sinf(a);
    out[idx]  = e + pe;
}

// ---------------- tiled f32 GEMM: C[M,N] = A[M,K] @ W[K,N] + bias ----------------
#define TILE 64
#define KT   16
__global__ __launch_bounds__(256) void gemm_bias_kernel(const float* __restrict__ A,
        const void* __restrict__ W, size_t woff, const void* __restrict__ bias, size_t boff,
        float* __restrict__ C, int M, int N, int K, int relu, const int* __restrict__ flagp)
{
    const int mode = flagp[0];
    __shared__ float As[KT][TILE];
    __shared__ float Bs[KT][TILE];
    int tid = threadIdx.x;
    int ty = tid >> 4, tx = tid & 15;
    int m0 = blockIdx.y * TILE, n0 = blockIdx.x * TILE;
    float acc[4][4] = {};
    for (int k0 = 0; k0 < K; k0 += KT) {
        {   // stage A tile 64x16 (f32, float4 loads)
            int r = tid >> 2;
            int c = (tid & 3) * 4;
            const float4 v = *reinterpret_cast<const float4*>(A + (size_t)(m0 + r) * K + k0 + c);
            As[c + 0][r] = v.x; As[c + 1][r] = v.y; As[c + 2][r] = v.z; As[c + 3][r] = v.w;
        }
        {   // stage W tile 16x64
            int r = tid >> 4;
            int c = (tid & 15) * 4;
            float4 wv = ldp4(W, woff + (size_t)(k0 + r) * N + n0 + c, mode);
            Bs[r][c + 0] = wv.x; Bs[r][c + 1] = wv.y; Bs[r][c + 2] = wv.z; Bs[r][c + 3] = wv.w;
        }
        __syncthreads();
#pragma unroll
        for (int kk = 0; kk < KT; ++kk) {
            float4 a4 = *reinterpret_cast<const float4*>(&As[kk][ty * 4]);
            float4 b4 = *reinterpret_cast<const float4*>(&Bs[kk][tx * 4]);
            float a[4] = {a4.x, a4.y, a4.z, a4.w};
            float b[4] = {b4.x, b4.y, b4.z, b4.w};
#pragma unroll
            for (int i = 0; i < 4; ++i)
#pragma unroll
                for (int j = 0; j < 4; ++j)
                    acc[i][j] = fmaf(a[i], b[j], acc[i][j]);
        }
        __syncthreads();
    }
#pragma unroll
    for (int i = 0; i < 4; ++i) {
        int m = m0 + ty * 4 + i;
#pragma unroll
        for (int j = 0; j < 4; ++j) {
            int n = n0 + tx * 4 + j;
            float v = acc[i][j] + ldp(bias, boff + n, mode);
            if (relu) v = fmaxf(v, 0.0f);
            C[(size_t)m * N + n] = v;
        }
    }
}

// ---------------- fused attention: one block per (b,h,q) row ----------------
__global__ __launch_bounds__(256) void attn_kernel(const float* __restrict__ Q,
        const float* __restrict__ Kv, const float* __restrict__ Vv,
        const int* __restrict__ kv_tok, float* __restrict__ O,
        int Sk, int causal)
{
    __shared__ float qs[DH_];
    __shared__ float ps[512];
    __shared__ float red[256];
    int bid = blockIdx.x;
    int q  = bid & 511;
    int bh = bid >> 9;
    int h  = bh & (NH_ - 1);
    int b  = bh >> 3;
    int tid = threadIdx.x;

    const float* qrow = Q + ((size_t)(b * 512 + q)) * D_ + h * DH_;
    if (tid < DH_) qs[tid] = qrow[tid];
    __syncthreads();

    const float scale = 0.125f;  // 1/sqrt(64)
    float lmax = -INFINITY;
    for (int k = tid; k < Sk; k += 256) {
        float s;
        bool masked = (causal && k > q) || (kv_tok[b * Sk + k] == 0);
        if (masked) {
            s = -INFINITY;
        } else {
            const float* krow = Kv + ((size_t)(b * Sk + k)) * D_ + h * DH_;
            float dot = 0.0f;
#pragma unroll
            for (int d = 0; d < DH_; ++d) dot = fmaf(qs[d], krow[d], dot);
            s = dot * scale;
        }
        ps[k] = s;
        lmax = fmaxf(lmax, s);
    }
    red[tid] = lmax; __syncthreads();
    for (int o = 128; o > 0; o >>= 1) {
        if (tid < o) red[tid] = fmaxf(red[tid], red[tid + o]);
        __syncthreads();
    }
    float m = red[0];
    __syncthreads();

    float lsum = 0.0f;
    for (int k = tid; k < Sk; k += 256) {
        float e = (m == -INFINITY) ? 0.0f : __expf(ps[k] - m);
        ps[k] = e;
        lsum += e;
    }
    red[tid] = lsum; __syncthreads();
    for (int o = 128; o > 0; o >>= 1) {
        if (tid < o) red[tid] += red[tid + o];
        __syncthreads();
    }
    float l = red[0];
    float inv = (l > 0.0f) ? 1.0f / l : 0.0f;   // fully-masked row -> zeros
    __syncthreads();

    int d = tid & (DH_ - 1), g = tid >> 6;      // 4 k-groups x 64 dims
    float acc = 0.0f;
    for (int k = g; k < Sk; k += 4)
        acc = fmaf(ps[k], Vv[((size_t)(b * Sk + k)) * D_ + h * DH_ + d], acc);
    red[tid] = acc;
    __syncthreads();
    if (tid < DH_) {
        float o = (red[tid] + red[64 + tid] + red[128 + tid] + red[192 + tid]) * inv;
        O[((size_t)(b * 512 + q)) * D_ + h * DH_ + tid] = o;
    }
}

// ---------------- residual add + LayerNorm (in-place on X) ----------------
__global__ __launch_bounds__(256) void add_ln_kernel(float* __restrict__ X,
        const float* __restrict__ R, const void* __restrict__ ln, size_t goff,
        const int* __restrict__ flagp)
{
    const int mode = flagp[0];
    __shared__ float red[256];
    int row = blockIdx.x, tid = threadIdx.x;
    size_t base = (size_t)row * D_;
    float v0 = X[base + tid] + R[base + tid];
    float v1 = X[base + 256 + tid] + R[base + 256 + tid];
    red[tid] = v0 + v1; __syncthreads();
    for (int o = 128; o > 0; o >>= 1) {
        if (tid < o) red[tid] += red[tid + o];
        __syncthreads();
    }
    float mu = red[0] * (1.0f / (float)D_);
    __syncthreads();
    float d0 = v0 - mu, d1 = v1 - mu;
    red[tid] = d0 * d0 + d1 * d1; __syncthreads();
    for (int o = 128; o > 0; o >>= 1) {
        if (tid < o) red[tid] += red[tid + o];
        __syncthreads();
    }
    float inv = rsqrtf(red[0] * (1.0f / (float)D_) + 1e-5f);
    X[base + tid]       = d0 * inv * ldp(ln, goff + tid, mode)       + ldp(ln, goff + D_ + tid, mode);
    X[base + 256 + tid] = d1 * inv * ldp(ln, goff + 256 + tid, mode) + ldp(ln, goff + D_ + 256 + tid, mode);
}

// ---------------- f32 -> output (bf16 or f32 per mode) ----------------
__global__ __launch_bounds__(256) void to_out_kernel(const float* __restrict__ in,
        void* __restrict__ out, int n, const int* __restrict__ flagp)
{
    const int mode = flagp[0];
    int i = blockIdx.x * 256 + threadIdx.x;
    if (i < n) {
        float v = in[i];
        if (mode) ((float*)out)[i] = v;
        else      ((__hip_bfloat16*)out)[i] = __float2bfloat16(v);
    }
}

extern "C" void kernel_launch(void* const* d_in, const int* in_sizes, int n_in,
                              void* d_out, int out_size, void* d_ws, size_t ws_size,
                              hipStream_t stream) {
    const int* tin  = (const int*)d_in[0];
    const int* tout = (const int*)d_in[1];
    const void* emi = d_in[2];
    const void* emo = d_in[3];
    const void* eaw = d_in[4];
    const void* eab = d_in[5];
    const void* eln = d_in[6];
    const void* ew1 = d_in[7];
    const void* eb1 = d_in[8];
    const void* ew2 = d_in[9];
    const void* eb2 = d_in[10];
    const void* dsw = d_in[11];
    const void* dsb = d_in[12];
    const void* dcw = d_in[13];
    const void* dcb = d_in[14];
    const void* dln = d_in[15];
    const void* dw1 = d_in[16];
    const void* db1 = d_in[17];
    const void* dw2 = d_in[18];
    const void* db2 = d_in[19];

    // ws layout (<= 56.1 MB): flag pad(64) | X | Y | P | TMP(4 bufs / FFN hidden)
    int*   flagp = (int*)d_ws;
    float* base  = (float*)d_ws + 64;
    float* X   = base;
    float* Y   = X + MD_;
    float* P   = Y + MD_;
    float* TMP = P + MD_;            // 4*MD_ floats
    float* Qb  = TMP;
    float* Kb  = TMP + MD_;
    float* Vb  = TMP + 2 * (size_t)MD_;
    float* CTX = TMP + 3 * (size_t)MD_;
    float* HB  = TMP;                // overlays Qb..CTX during FFN (M_ x HID_)

    auto gemm = [&](const float* A, const void* W, size_t woff, const void* bias, size_t boff,
                    float* C, int N, int K, int relu) {
        dim3 grid(N / TILE, M_ / TILE);
        gemm_bias_kernel<<<grid, 256, 0, stream>>>(A, W, woff, bias, boff, C, M_, N, K, relu, flagp);
    };

    detect_kernel<<<1, 256, 0, stream>>>(emi, flagp);

    // embeddings + PE
    embed_pe_kernel<<<(M_ * D_) / 256, 256, 0, stream>>>(tin, emi, X, flagp);
    embed_pe_kernel<<<(M_ * D_) / 256, 256, 0, stream>>>(tout, emo, Y, flagp);

    const size_t WDD = (size_t)D_ * D_;

    // ---- encoder ----
    for (int l = 0; l < L_; ++l) {
        size_t w = (size_t)l * 4 * WDD, bb = (size_t)l * 4 * D_;
        gemm(X, eaw, w + 0 * WDD, eab, bb + 0 * D_, Qb, D_, D_, 0);
        gemm(X, eaw, w + 1 * WDD, eab, bb + 1 * D_, Kb, D_, D_, 0);
        gemm(X, eaw, w + 2 * WDD, eab, bb + 2 * D_, Vb, D_, D_, 0);
        attn_kernel<<<B_ * NH_ * S_, 256, 0, stream>>>(Qb, Kb, Vb, tin, CTX, S_, 0);
        gemm(CTX, eaw, w + 3 * WDD, eab, bb + 3 * D_, P, D_, D_, 0);
        add_ln_kernel<<<M_, 256, 0, stream>>>(X, P, eln, ((size_t)l * 2 + 0) * 2 * D_, flagp);
        gemm(X, ew1, (size_t)l * D_ * HID_, eb1, (size_t)l * HID_, HB, HID_, D_, 1);
        gemm(HB, ew2, (size_t)l * HID_ * D_, eb2, (size_t)l * D_, P, D_, HID_, 0);
        add_ln_kernel<<<M_, 256, 0, stream>>>(X, P, eln, ((size_t)l * 2 + 1) * 2 * D_, flagp);
    }

    // ---- decoder ----
    for (int l = 0; l < L_; ++l) {
        // self-attention (causal)
        size_t w = (size_t)l * 4 * WDD, bb = (size_t)l * 4 * D_;
        gemm(Y, dsw, w + 0 * WDD, dsb, bb + 0 * D_, Qb, D_, D_, 0);
        gemm(Y, dsw, w + 1 * WDD, dsb, bb + 1 * D_, Kb, D_, D_, 0);
        gemm(Y, dsw, w + 2 * WDD, dsb, bb + 2 * D_, Vb, D_, D_, 0);
        attn_kernel<<<B_ * NH_ * T_, 256, 0, stream>>>(Qb, Kb, Vb, tout, CTX, T_, 1);
        gemm(CTX, dsw, w + 3 * WDD, dsb, bb + 3 * D_, P, D_, D_, 0);
        add_ln_kernel<<<M_, 256, 0, stream>>>(Y, P, dln, ((size_t)l * 3 + 0) * 2 * D_, flagp);
        // cross-attention (q from Y, kv from X)
        gemm(Y, dcw, w + 0 * WDD, dcb, bb + 0 * D_, Qb, D_, D_, 0);
        gemm(X, dcw, w + 1 * WDD, dcb, bb + 1 * D_, Kb, D_, D_, 0);
        gemm(X, dcw, w + 2 * WDD, dcb, bb + 2 * D_, Vb, D_, D_, 0);
        attn_kernel<<<B_ * NH_ * T_, 256, 0, stream>>>(Qb, Kb, Vb, tin, CTX, S_, 0);
        gemm(CTX, dcw, w + 3 * WDD, dcb, bb + 3 * D_, P, D_, D_, 0);
        add_ln_kernel<<<M_, 256, 0, stream>>>(Y, P, dln, ((size_t)l * 3 + 1) * 2 * D_, flagp);
        // FFN
        gemm(Y, dw1, (size_t)l * D_ * HID_, db1, (size_t)l * HID_, HB, HID_, D_, 1);
        gemm(HB, dw2, (size_t)l * HID_ * D_, db2, (size_t)l * D_, P, D_, HID_, 0);
        add_ln_kernel<<<M_, 256, 0, stream>>>(Y, P, dln, ((size_t)l * 3 + 2) * 2 * D_, flagp);
    }

    to_out_kernel<<<(out_size + 255) / 256, 256, 0, stream>>>(Y, d_out, out_size, flagp);
}

// Round 3
// 8648.467 us; speedup vs baseline: 2.7197x; 2.7197x over previous
//
#include <hip/hip_runtime.h>
#include <hip/hip_bf16.h>

#define D_   512
#define HID_ 2048
#define NH_  8
#define DH_  64
#define L_   6
#define B_   8
#define S_   512
#define T_   512
#define M_   4096            // B_*S_ rows
#define MD_  (M_ * D_)       // floats per activation buffer

__device__ __forceinline__ float bf2f(unsigned short u) {
    union { unsigned int i; float f; } x; x.i = ((unsigned int)u) << 16; return x.f;
}

// Dual-dtype param loads: mode==1 -> storage is float32, mode==0 -> bf16 (ushort).
__device__ __forceinline__ float ldp(const void* p, size_t i, int mode) {
    return mode ? ((const float*)p)[i] : bf2f(((const unsigned short*)p)[i]);
}
__device__ __forceinline__ float4 ldp4(const void* p, size_t i, int mode) {
    if (mode) return *reinterpret_cast<const float4*>((const float*)p + i);
    short4 v = *reinterpret_cast<const short4*>((const unsigned short*)p + i);
    return make_float4(bf2f((unsigned short)v.x), bf2f((unsigned short)v.y),
                       bf2f((unsigned short)v.z), bf2f((unsigned short)v.w));
}

// ---------------- dtype probe (see round 1 notes) ----------------
__global__ __launch_bounds__(256) void detect_kernel(const void* em, int* flagp) {
    __shared__ int big, zc;
    if (threadIdx.x == 0) { big = 0; zc = 0; }
    __syncthreads();
    const unsigned short* u = (const unsigned short*)em;
    int lbig = 0, lzc = 0;
    for (int i = threadIdx.x; i < 2048; i += 256) {
        unsigned short x = u[512 + i];
        float v = bf2f(x);
        if (!(fabsf(v) < 1000.0f)) lbig = 1;
        if ((((512 + i) & 1) == 0) && ((x & 0x7fff) == 0)) lzc++;
    }
    if (lbig) atomicOr(&big, 1);
    atomicAdd(&zc, lzc);
    __syncthreads();
    if (threadIdx.x == 0) flagp[0] = (big || zc >= 1000) ? 1 : 0;
}

// ---------------- embedding + positional encoding ----------------
__global__ __launch_bounds__(256) void embed_pe_kernel(const int* __restrict__ tok,
        const void* __restrict__ em, float* __restrict__ out, const int* __restrict__ flagp)
{
    const int mode = flagp[0];
    int idx = blockIdx.x * 256 + threadIdx.x;
    int d   = idx & (D_ - 1);
    int row = idx >> 9;
    int s   = row & (S_ - 1);
    int t   = tok[row];
    float e = ldp(em, (size_t)t * D_ + d, mode);
    int d2  = d & ~1;
    float div = expf((float)d2 * (-9.210340371976184f / (float)D_));
    float a   = (float)s * div;
    float pe  = (d & 1) ? cosf(a) : sinf(a);
    out[idx]  = e + pe;
}

// ---------------- tiled f32 GEMM: C[M,N] = A[M,K] @ W[K,N] + bias ----------------
#define TILE 64
#define KT   16
__global__ __launch_bounds__(256) void gemm_bias_kernel(const float* __restrict__ A,
        const void* __restrict__ W, size_t woff, const void* __restrict__ bias, size_t boff,
        float* __restrict__ C, int M, int N, int K, int relu, const int* __restrict__ flagp)
{
    const int mode = flagp[0];
    __shared__ float As[KT][TILE];
    __shared__ float Bs[KT][TILE];
    int tid = threadIdx.x;
    int ty = tid >> 4, tx = tid & 15;
    int m0 = blockIdx.y * TILE, n0 = blockIdx.x * TILE;
    float acc[4][4] = {};
    for (int k0 = 0; k0 < K; k0 += KT) {
        {
            int r = tid >> 2;
            int c = (tid & 3) * 4;
            const float4 v = *reinterpret_cast<const float4*>(A + (size_t)(m0 + r) * K + k0 + c);
            As[c + 0][r] = v.x; As[c + 1][r] = v.y; As[c + 2][r] = v.z; As[c + 3][r] = v.w;
        }
        {
            int r = tid >> 4;
            int c = (tid & 15) * 4;
            float4 wv = ldp4(W, woff + (size_t)(k0 + r) * N + n0 + c, mode);
            Bs[r][c + 0] = wv.x; Bs[r][c + 1] = wv.y; Bs[r][c + 2] = wv.z; Bs[r][c + 3] = wv.w;
        }
        __syncthreads();
#pragma unroll
        for (int kk = 0; kk < KT; ++kk) {
            float4 a4 = *reinterpret_cast<const float4*>(&As[kk][ty * 4]);
            float4 b4 = *reinterpret_cast<const float4*>(&Bs[kk][tx * 4]);
            float a[4] = {a4.x, a4.y, a4.z, a4.w};
            float b[4] = {b4.x, b4.y, b4.z, b4.w};
#pragma unroll
            for (int i = 0; i < 4; ++i)
#pragma unroll
                for (int j = 0; j < 4; ++j)
                    acc[i][j] = fmaf(a[i], b[j], acc[i][j]);
        }
        __syncthreads();
    }
#pragma unroll
    for (int i = 0; i < 4; ++i) {
        int m = m0 + ty * 4 + i;
#pragma unroll
        for (int j = 0; j < 4; ++j) {
            int n = n0 + tx * 4 + j;
            float v = acc[i][j] + ldp(bias, boff + n, mode);
            if (relu) v = fmaxf(v, 0.0f);
            C[(size_t)m * N + n] = v;
        }
    }
}

// ---------------- flash-style tiled attention ----------------
// One block = (b, h, 64-row q-tile). 256 threads: thread (qg=tid>>4, kg=tid&15)
// owns a 4x4 sub-tile. Q,K stored transposed in LDS ([d][row], stride 68) so
// the score inner loop is two ds_read_b128 per d. Online softmax in registers,
// 16-lane shfl row reductions. P -> LDS -> PV with V in natural [k][d] layout.
#define LSTR 68
__global__ __launch_bounds__(256) void fattn_kernel(const float* __restrict__ Q,
        const float* __restrict__ Kv, const float* __restrict__ Vv,
        const int* __restrict__ kv_tok, float* __restrict__ O,
        int Sk, int causal)
{
    __shared__ float Qs[64 * LSTR];    // [d][q] transposed
    __shared__ float KVs[64 * LSTR];   // K phase: [d][k] transposed; V phase: [k][d]
    __shared__ float Ps[64 * LSTR];    // [q][k]
    int tid = threadIdx.x;
    int bid = blockIdx.x;
    int tq = bid & 7;
    int h  = (bid >> 3) & 7;
    int b  = bid >> 6;
    int q0 = tq * 64;
    const int qg = tid >> 4, kg = tid & 15;
    const int sr = tid >> 2, sc0 = (tid & 3) * 16;   // staging: row, col base

    {   // stage Q transposed (once)
        const float* qp = Q + ((size_t)(b * 512 + q0 + sr)) * D_ + h * DH_ + sc0;
#pragma unroll
        for (int u = 0; u < 4; ++u) {
            float4 v = *reinterpret_cast<const float4*>(qp + u * 4);
            int c = sc0 + u * 4;
            Qs[(c + 0) * LSTR + sr] = v.x;
            Qs[(c + 1) * LSTR + sr] = v.y;
            Qs[(c + 2) * LSTR + sr] = v.z;
            Qs[(c + 3) * LSTR + sr] = v.w;
        }
    }

    float m[4], l[4], o[4][4];
#pragma unroll
    for (int i = 0; i < 4; ++i) {
        m[i] = -INFINITY; l[i] = 0.0f;
#pragma unroll
        for (int j = 0; j < 4; ++j) o[i][j] = 0.0f;
    }

    const int nkt = causal ? (tq + 1) : (Sk >> 6);
    for (int kt = 0; kt < nkt; ++kt) {
        int k0 = kt * 64;
        __syncthreads();   // prev PV done (and Q staged, first iter)
        {   // stage K transposed
            const float* kp = Kv + ((size_t)(b * Sk + k0 + sr)) * D_ + h * DH_ + sc0;
#pragma unroll
            for (int u = 0; u < 4; ++u) {
                float4 v = *reinterpret_cast<const float4*>(kp + u * 4);
                int c = sc0 + u * 4;
                KVs[(c + 0) * LSTR + sr] = v.x;
                KVs[(c + 1) * LSTR + sr] = v.y;
                KVs[(c + 2) * LSTR + sr] = v.z;
                KVs[(c + 3) * LSTR + sr] = v.w;
            }
        }
        __syncthreads();

        // scores: s[i][j] = Q[q0+qg*4+i] . K[k0+kg*4+j]
        float s[4][4] = {};
        for (int d = 0; d < 64; ++d) {
            float4 a4 = *reinterpret_cast<const float4*>(&Qs[d * LSTR + qg * 4]);
            float4 b4 = *reinterpret_cast<const float4*>(&KVs[d * LSTR + kg * 4]);
            float a[4] = {a4.x, a4.y, a4.z, a4.w};
            float bb[4] = {b4.x, b4.y, b4.z, b4.w};
#pragma unroll
            for (int i = 0; i < 4; ++i)
#pragma unroll
                for (int j = 0; j < 4; ++j)
                    s[i][j] = fmaf(a[i], bb[j], s[i][j]);
        }

        // mask + scale
        int kbase = k0 + kg * 4;
        int tk[4];
#pragma unroll
        for (int j = 0; j < 4; ++j) tk[j] = kv_tok[b * Sk + kbase + j];
#pragma unroll
        for (int i = 0; i < 4; ++i) {
            int qrow = q0 + qg * 4 + i;
#pragma unroll
            for (int j = 0; j < 4; ++j) {
                bool masked = (causal && (kbase + j > qrow)) || (tk[j] == 0);
                s[i][j] = masked ? -INFINITY : s[i][j] * 0.125f;
            }
        }

        // online softmax update + write P tile
#pragma unroll
        for (int i = 0; i < 4; ++i) {
            float tm = fmaxf(fmaxf(s[i][0], s[i][1]), fmaxf(s[i][2], s[i][3]));
            tm = fmaxf(tm, __shfl_xor(tm, 1, 16));
            tm = fmaxf(tm, __shfl_xor(tm, 2, 16));
            tm = fmaxf(tm, __shfl_xor(tm, 4, 16));
            tm = fmaxf(tm, __shfl_xor(tm, 8, 16));
            float mnew = fmaxf(m[i], tm);
            float alpha = (mnew == -INFINITY) ? 1.0f : __expf(m[i] - mnew);
            float4 p4;
            float p[4];
#pragma unroll
            for (int j = 0; j < 4; ++j)
                p[j] = (s[i][j] == -INFINITY) ? 0.0f : __expf(s[i][j] - mnew);
            p4.x = p[0]; p4.y = p[1]; p4.z = p[2]; p4.w = p[3];
            *reinterpret_cast<float4*>(&Ps[(qg * 4 + i) * LSTR + kg * 4]) = p4;
            float rs = p[0] + p[1] + p[2] + p[3];
            rs += __shfl_xor(rs, 1, 16);
            rs += __shfl_xor(rs, 2, 16);
            rs += __shfl_xor(rs, 4, 16);
            rs += __shfl_xor(rs, 8, 16);
            l[i] = l[i] * alpha + rs;
            m[i] = mnew;
#pragma unroll
            for (int j = 0; j < 4; ++j) o[i][j] *= alpha;
        }
        __syncthreads();   // Ps visible; K reads done

        {   // stage V (natural [k][d] layout, float4)
            const float* vp = Vv + ((size_t)(b * Sk + k0 + sr)) * D_ + h * DH_ + sc0;
#pragma unroll
            for (int u = 0; u < 4; ++u) {
                float4 v = *reinterpret_cast<const float4*>(vp + u * 4);
                *reinterpret_cast<float4*>(&KVs[sr * LSTR + sc0 + u * 4]) = v;
            }
        }
        __syncthreads();   // Vs visible

        // o[i][j] += sum_k P[q][k] * V[k][d]
        for (int k = 0; k < 64; ++k) {
            float4 v4 = *reinterpret_cast<const float4*>(&KVs[k * LSTR + kg * 4]);
            float vv[4] = {v4.x, v4.y, v4.z, v4.w};
            float p0 = Ps[(qg * 4 + 0) * LSTR + k];
            float p1 = Ps[(qg * 4 + 1) * LSTR + k];
            float p2 = Ps[(qg * 4 + 2) * LSTR + k];
            float p3 = Ps[(qg * 4 + 3) * LSTR + k];
#pragma unroll
            for (int j = 0; j < 4; ++j) {
                o[0][j] = fmaf(p0, vv[j], o[0][j]);
                o[1][j] = fmaf(p1, vv[j], o[1][j]);
                o[2][j] = fmaf(p2, vv[j], o[2][j]);
                o[3][j] = fmaf(p3, vv[j], o[3][j]);
            }
        }
    }

#pragma unroll
    for (int i = 0; i < 4; ++i) {
        float inv = (l[i] > 0.0f) ? 1.0f / l[i] : 0.0f;
        float4 r;
        r.x = o[i][0] * inv; r.y = o[i][1] * inv; r.z = o[i][2] * inv; r.w = o[i][3] * inv;
        *reinterpret_cast<float4*>(
            &O[((size_t)(b * 512 + q0 + qg * 4 + i)) * D_ + h * DH_ + kg * 4]) = r;
    }
}

// ---------------- residual add + LayerNorm (in-place on X) ----------------
__global__ __launch_bounds__(256) void add_ln_kernel(float* __restrict__ X,
        const float* __restrict__ R, const void* __restrict__ ln, size_t goff,
        const int* __restrict__ flagp)
{
    const int mode = flagp[0];
    __shared__ float red[256];
    int row = blockIdx.x, tid = threadIdx.x;
    size_t base = (size_t)row * D_;
    float v0 = X[base + tid] + R[base + tid];
    float v1 = X[base + 256 + tid] + R[base + 256 + tid];
    red[tid] = v0 + v1; __syncthreads();
    for (int o = 128; o > 0; o >>= 1) {
        if (tid < o) red[tid] += red[tid + o];
        __syncthreads();
    }
    float mu = red[0] * (1.0f / (float)D_);
    __syncthreads();
    float d0 = v0 - mu, d1 = v1 - mu;
    red[tid] = d0 * d0 + d1 * d1; __syncthreads();
    for (int o = 128; o > 0; o >>= 1) {
        if (tid < o) red[tid] += red[tid + o];
        __syncthreads();
    }
    float inv = rsqrtf(red[0] * (1.0f / (float)D_) + 1e-5f);
    X[base + tid]       = d0 * inv * ldp(ln, goff + tid, mode)       + ldp(ln, goff + D_ + tid, mode);
    X[base + 256 + tid] = d1 * inv * ldp(ln, goff + 256 + tid, mode) + ldp(ln, goff + D_ + 256 + tid, mode);
}

// ---------------- f32 -> output (bf16 or f32 per mode) ----------------
__global__ __launch_bounds__(256) void to_out_kernel(const float* __restrict__ in,
        void* __restrict__ out, int n, const int* __restrict__ flagp)
{
    const int mode = flagp[0];
    int i = blockIdx.x * 256 + threadIdx.x;
    if (i < n) {
        float v = in[i];
        if (mode) ((float*)out)[i] = v;
        else      ((__hip_bfloat16*)out)[i] = __float2bfloat16(v);
    }
}

extern "C" void kernel_launch(void* const* d_in, const int* in_sizes, int n_in,
                              void* d_out, int out_size, void* d_ws, size_t ws_size,
                              hipStream_t stream) {
    const int* tin  = (const int*)d_in[0];
    const int* tout = (const int*)d_in[1];
    const void* emi = d_in[2];
    const void* emo = d_in[3];
    const void* eaw = d_in[4];
    const void* eab = d_in[5];
    const void* eln = d_in[6];
    const void* ew1 = d_in[7];
    const void* eb1 = d_in[8];
    const void* ew2 = d_in[9];
    const void* eb2 = d_in[10];
    const void* dsw = d_in[11];
    const void* dsb = d_in[12];
    const void* dcw = d_in[13];
    const void* dcb = d_in[14];
    const void* dln = d_in[15];
    const void* dw1 = d_in[16];
    const void* db1 = d_in[17];
    const void* dw2 = d_in[18];
    const void* db2 = d_in[19];

    int*   flagp = (int*)d_ws;
    float* base  = (float*)d_ws + 64;
    float* X   = base;
    float* Y   = X + MD_;
    float* P   = Y + MD_;
    float* TMP = P + MD_;
    float* Qb  = TMP;
    float* Kb  = TMP + MD_;
    float* Vb  = TMP + 2 * (size_t)MD_;
    float* CTX = TMP + 3 * (size_t)MD_;
    float* HB  = TMP;                // overlays Qb..CTX during FFN

    auto gemm = [&](const float* A, const void* W, size_t woff, const void* bias, size_t boff,
                    float* C, int N, int K, int relu) {
        dim3 grid(N / TILE, M_ / TILE);
        gemm_bias_kernel<<<grid, 256, 0, stream>>>(A, W, woff, bias, boff, C, M_, N, K, relu, flagp);
    };

    detect_kernel<<<1, 256, 0, stream>>>(emi, flagp);

    embed_pe_kernel<<<(M_ * D_) / 256, 256, 0, stream>>>(tin, emi, X, flagp);
    embed_pe_kernel<<<(M_ * D_) / 256, 256, 0, stream>>>(tout, emo, Y, flagp);

    const size_t WDD = (size_t)D_ * D_;
    const int AGRID = B_ * NH_ * 8;   // 512 blocks

    // ---- encoder ----
    for (int l = 0; l < L_; ++l) {
        size_t w = (size_t)l * 4 * WDD, bb = (size_t)l * 4 * D_;
        gemm(X, eaw, w + 0 * WDD, eab, bb + 0 * D_, Qb, D_, D_, 0);
        gemm(X, eaw, w + 1 * WDD, eab, bb + 1 * D_, Kb, D_, D_, 0);
        gemm(X, eaw, w + 2 * WDD, eab, bb + 2 * D_, Vb, D_, D_, 0);
        fattn_kernel<<<AGRID, 256, 0, stream>>>(Qb, Kb, Vb, tin, CTX, S_, 0);
        gemm(CTX, eaw, w + 3 * WDD, eab, bb + 3 * D_, P, D_, D_, 0);
        add_ln_kernel<<<M_, 256, 0, stream>>>(X, P, eln, ((size_t)l * 2 + 0) * 2 * D_, flagp);
        gemm(X, ew1, (size_t)l * D_ * HID_, eb1, (size_t)l * HID_, HB, HID_, D_, 1);
        gemm(HB, ew2, (size_t)l * HID_ * D_, eb2, (size_t)l * D_, P, D_, HID_, 0);
        add_ln_kernel<<<M_, 256, 0, stream>>>(X, P, eln, ((size_t)l * 2 + 1) * 2 * D_, flagp);
    }

    // ---- decoder ----
    for (int l = 0; l < L_; ++l) {
        size_t w = (size_t)l * 4 * WDD, bb = (size_t)l * 4 * D_;
        gemm(Y, dsw, w + 0 * WDD, dsb, bb + 0 * D_, Qb, D_, D_, 0);
        gemm(Y, dsw, w + 1 * WDD, dsb, bb + 1 * D_, Kb, D_, D_, 0);
        gemm(Y, dsw, w + 2 * WDD, dsb, bb + 2 * D_, Vb, D_, D_, 0);
        fattn_kernel<<<AGRID, 256, 0, stream>>>(Qb, Kb, Vb, tout, CTX, T_, 1);
        gemm(CTX, dsw, w + 3 * WDD, dsb, bb + 3 * D_, P, D_, D_, 0);
        add_ln_kernel<<<M_, 256, 0, stream>>>(Y, P, dln, ((size_t)l * 3 + 0) * 2 * D_, flagp);
        gemm(Y, dcw, w + 0 * WDD, dcb, bb + 0 * D_, Qb, D_, D_, 0);
        gemm(X, dcw, w + 1 * WDD, dcb, bb + 1 * D_, Kb, D_, D_, 0);
        gemm(X, dcw, w + 2 * WDD, dcb, bb + 2 * D_, Vb, D_, D_, 0);
        fattn_kernel<<<AGRID, 256, 0, stream>>>(Qb, Kb, Vb, tin, CTX, S_, 0);
        gemm(CTX, dcw, w + 3 * WDD, dcb, bb + 3 * D_, P, D_, D_, 0);
        add_ln_kernel<<<M_, 256, 0, stream>>>(Y, P, dln, ((size_t)l * 3 + 1) * 2 * D_, flagp);
        gemm(Y, dw1, (size_t)l * D_ * HID_, db1, (size_t)l * HID_, HB, HID_, D_, 1);
        gemm(HB, dw2, (size_t)l * HID_ * D_, db2, (size_t)l * D_, P, D_, HID_, 0);
        add_ln_kernel<<<M_, 256, 0, stream>>>(Y, P, dln, ((size_t)l * 3 + 2) * 2 * D_, flagp);
    }

    to_out_kernel<<<(out_size + 255) / 256, 256, 0, stream>>>(Y, d_out, out_size, flagp);
}

// Round 4
// 4447.417 us; speedup vs baseline: 5.2888x; 1.9446x over previous
//
#include <hip/hip_runtime.h>
#include <hip/hip_bf16.h>

#define D_   512
#define HID_ 2048
#define NH_  8
#define DH_  64
#define L_   6
#define B_   8
#define S_   512
#define T_   512
#define M_   4096            // B_*S_ rows
#define MD_  (M_ * D_)
#define QSTR 1536            // packed QKV row stride

typedef unsigned short ushort_t;
typedef __attribute__((ext_vector_type(8))) short bf16x8;
typedef __attribute__((ext_vector_type(4))) float f32x4;

__device__ __forceinline__ float bf2f(unsigned short u) {
    union { unsigned int i; float f; } x; x.i = ((unsigned int)u) << 16; return x.f;
}
__device__ __forceinline__ unsigned short f2bf(float f) {
    union { float f; unsigned int u; } x; x.f = f;
    unsigned int r = (x.u + 0x7fffu + ((x.u >> 16) & 1u)) >> 16;
    return (unsigned short)r;
}
// Dual-dtype param loads: mode==1 -> storage f32, mode==0 -> bf16.
__device__ __forceinline__ float ldp(const void* p, size_t i, int mode) {
    return mode ? ((const float*)p)[i] : bf2f(((const unsigned short*)p)[i]);
}

// ---------------- dtype probe (see round 1 notes) ----------------
__global__ __launch_bounds__(256) void detect_kernel(const void* em, int* flagp) {
    __shared__ int big, zc;
    if (threadIdx.x == 0) { big = 0; zc = 0; }
    __syncthreads();
    const unsigned short* u = (const unsigned short*)em;
    int lbig = 0, lzc = 0;
    for (int i = threadIdx.x; i < 2048; i += 256) {
        unsigned short x = u[512 + i];
        float v = bf2f(x);
        if (!(fabsf(v) < 1000.0f)) lbig = 1;
        if ((((512 + i) & 1) == 0) && ((x & 0x7fff) == 0)) lzc++;
    }
    if (lbig) atomicOr(&big, 1);
    atomicAdd(&zc, lzc);
    __syncthreads();
    if (threadIdx.x == 0) flagp[0] = (big || zc >= 1000) ? 1 : 0;
}

// ---------------- embedding + PE: writes f32 stream + bf16 shadow ----------------
__global__ __launch_bounds__(256) void embed_pe_kernel(const int* __restrict__ tok,
        const void* __restrict__ em, float* __restrict__ out,
        unsigned short* __restrict__ outb, const int* __restrict__ flagp)
{
    const int mode = flagp[0];
    int idx = blockIdx.x * 256 + threadIdx.x;
    int d   = idx & (D_ - 1);
    int row = idx >> 9;
    int s   = row & (S_ - 1);
    int t   = tok[row];
    float e = ldp(em, (size_t)t * D_ + d, mode);
    int d2  = d & ~1;
    float div = expf((float)d2 * (-9.210340371976184f / (float)D_));
    float a   = (float)s * div;
    float pe  = (d & 1) ? cosf(a) : sinf(a);
    float v   = e + pe;
    out[idx]  = v;
    outb[idx] = f2bf(v);
}

// ---------------- bf16 MFMA GEMM ----------------
// C[M,N] = A[M,K](bf16) @ W[K,N](bf16 or f32 per mode) + bias.
// Block 256 thr = 4 waves (2x2). Tile TM x 128, BK=32. Wave tile (TM/2) x 64,
// TMT x 4 accs of 16x16x32 MFMA. A LDS [m][k] pad->40, W LDS transposed [n][k]
// pad->40 (2-way bank aliasing only). nsub = width of each fused submatrix.
template<int TMT>
__global__ __launch_bounds__(256) void mfma_gemm(
        const unsigned short* __restrict__ A, int K,
        const void* __restrict__ W, size_t woff, int nsub,
        const void* __restrict__ bias, size_t boff,
        void* __restrict__ C, int ldc, int cmode /*0=f32,1=bf16*/, int relu,
        const int* __restrict__ flagp)
{
    constexpr int TM = TMT * 32;
    __shared__ unsigned short As[TM * 40];
    __shared__ unsigned short Bs[128 * 40];

    const int mode = __builtin_amdgcn_readfirstlane(flagp[0]);
    const int tid  = threadIdx.x;
    const int m0   = blockIdx.y * TM;
    const int n0   = blockIdx.x * 128;

    const size_t wbase = woff + (size_t)(n0 / nsub) * (size_t)K * nsub + (n0 % nsub);

    // A staging assignment
    constexpr int AEPT = TM / 8;       // bf16 elems per thread (16 or 8)
    constexpr int TPRA = 32 / AEPT;    // threads per A-row (2 or 4)
    const int ar = tid / TPRA;
    const int ac = (tid % TPRA) * AEPT;
    // B staging assignment: thread covers 8k x 2n patch
    const int n0t = 2 * (tid & 63);
    const int kb  = 8 * (tid >> 6);

    // wave/lane for MFMA
    const int lane = tid & 63;
    const int ln   = lane & 15;
    const int q    = lane >> 4;
    const int wave = tid >> 6;
    const int wm   = (wave >> 1) * (TMT * 16);
    const int wn   = (wave & 1) * 64;

    f32x4 acc[TMT][4];
#pragma unroll
    for (int i = 0; i < TMT; ++i)
#pragma unroll
        for (int j = 0; j < 4; ++j) acc[i][j] = (f32x4)0.0f;

    for (int k0 = 0; k0 < K; k0 += 32) {
        __syncthreads();
        {   // stage A [TM][32] -> As[m][k], stride 40
            const unsigned short* ap = A + (size_t)(m0 + ar) * K + k0 + ac;
#pragma unroll
            for (int u = 0; u < AEPT / 8; ++u) {
                uint4 v = *reinterpret_cast<const uint4*>(ap + u * 8);
                *reinterpret_cast<uint4*>(&As[ar * 40 + ac + u * 8]) = v;
            }
        }
        {   // stage W tile [32][128] transposed -> Bs[n][k], stride 40
            unsigned int lo[4], hi[4];
            if (mode == 0) {
                const unsigned short* wp = (const unsigned short*)W + wbase;
                unsigned int v[8];
#pragma unroll
                for (int r = 0; r < 8; ++r)
                    v[r] = *reinterpret_cast<const unsigned int*>(
                        wp + (size_t)(k0 + kb + r) * nsub + n0t);
#pragma unroll
                for (int p = 0; p < 4; ++p) {
                    lo[p] = (v[2*p] & 0xffffu) | (v[2*p+1] << 16);
                    hi[p] = (v[2*p] >> 16) | (v[2*p+1] & 0xffff0000u);
                }
            } else {
                const float* wp = (const float*)W + wbase;
                unsigned short a[8], b[8];
#pragma unroll
                for (int r = 0; r < 8; ++r) {
                    float2 f = *reinterpret_cast<const float2*>(
                        wp + (size_t)(k0 + kb + r) * nsub + n0t);
                    a[r] = f2bf(f.x); b[r] = f2bf(f.y);
                }
#pragma unroll
                for (int p = 0; p < 4; ++p) {
                    lo[p] = (unsigned int)a[2*p] | ((unsigned int)a[2*p+1] << 16);
                    hi[p] = (unsigned int)b[2*p] | ((unsigned int)b[2*p+1] << 16);
                }
            }
            *reinterpret_cast<uint4*>(&Bs[(n0t + 0) * 40 + kb]) = make_uint4(lo[0], lo[1], lo[2], lo[3]);
            *reinterpret_cast<uint4*>(&Bs[(n0t + 1) * 40 + kb]) = make_uint4(hi[0], hi[1], hi[2], hi[3]);
        }
        __syncthreads();

        bf16x8 af[TMT], bf[4];
#pragma unroll
        for (int i = 0; i < TMT; ++i)
            af[i] = *reinterpret_cast<const bf16x8*>(&As[(wm + i * 16 + ln) * 40 + q * 8]);
#pragma unroll
        for (int j = 0; j < 4; ++j)
            bf[j] = *reinterpret_cast<const bf16x8*>(&Bs[(wn + j * 16 + ln) * 40 + q * 8]);
#pragma unroll
        for (int i = 0; i < TMT; ++i)
#pragma unroll
            for (int j = 0; j < 4; ++j)
                acc[i][j] = __builtin_amdgcn_mfma_f32_16x16x32_bf16(af[i], bf[j], acc[i][j], 0, 0, 0);
    }

    // epilogue: bias (+relu), store f32 or bf16
    float bj[4];
#pragma unroll
    for (int j = 0; j < 4; ++j)
        bj[j] = ldp(bias, boff + (size_t)n0 + wn + j * 16 + ln, mode);
#pragma unroll
    for (int i = 0; i < TMT; ++i) {
#pragma unroll
        for (int j = 0; j < 4; ++j) {
            int n = n0 + wn + j * 16 + ln;
#pragma unroll
            for (int r = 0; r < 4; ++r) {
                int m = m0 + wm + i * 16 + q * 4 + r;
                float v = acc[i][j][r] + bj[j];
                if (relu) v = fmaxf(v, 0.0f);
                if (cmode == 0) ((float*)C)[(size_t)m * ldc + n] = v;
                else            ((unsigned short*)C)[(size_t)m * ldc + n] = f2bf(v);
            }
        }
    }
}

// ---------------- flash attention (bf16 packed QKV in, bf16 CTX out) ----------------
#define LSTR 68
__global__ __launch_bounds__(256) void fattn_kernel(const unsigned short* __restrict__ QKV,
        const int* __restrict__ kv_tok, unsigned short* __restrict__ O,
        int Sk, int causal)
{
    __shared__ float Qs[64 * LSTR];    // [d][q]
    __shared__ float KVs[64 * LSTR];   // K: [d][k]; V: [k][d]
    __shared__ float Ps[64 * LSTR];    // [q][k]
    int tid = threadIdx.x;
    int bid = blockIdx.x;
    int tq = bid & 7;
    int h  = (bid >> 3) & 7;
    int b  = bid >> 6;
    int q0 = tq * 64;
    const int qg = tid >> 4, kg = tid & 15;
    const int sr = tid >> 2, sc0 = (tid & 3) * 16;

    {   // stage Q transposed
        const unsigned short* p = QKV + (size_t)(b * 512 + q0 + sr) * QSTR + h * DH_ + sc0;
        uint4 u0 = *reinterpret_cast<const uint4*>(p);
        uint4 u1 = *reinterpret_cast<const uint4*>(p + 8);
        unsigned int w[8] = {u0.x, u0.y, u0.z, u0.w, u1.x, u1.y, u1.z, u1.w};
#pragma unroll
        for (int e = 0; e < 8; ++e) {
            Qs[(sc0 + 2 * e + 0) * LSTR + sr] = bf2f((unsigned short)(w[e] & 0xffffu));
            Qs[(sc0 + 2 * e + 1) * LSTR + sr] = bf2f((unsigned short)(w[e] >> 16));
        }
    }

    float m[4], l[4], o[4][4];
#pragma unroll
    for (int i = 0; i < 4; ++i) {
        m[i] = -INFINITY; l[i] = 0.0f;
#pragma unroll
        for (int j = 0; j < 4; ++j) o[i][j] = 0.0f;
    }

    const int nkt = causal ? (tq + 1) : (Sk >> 6);
    for (int kt = 0; kt < nkt; ++kt) {
        int k0 = kt * 64;
        __syncthreads();
        {   // stage K transposed (cols 512..1023 of QKV)
            const unsigned short* p = QKV + (size_t)(b * Sk + k0 + sr) * QSTR + 512 + h * DH_ + sc0;
            uint4 u0 = *reinterpret_cast<const uint4*>(p);
            uint4 u1 = *reinterpret_cast<const uint4*>(p + 8);
            unsigned int w[8] = {u0.x, u0.y, u0.z, u0.w, u1.x, u1.y, u1.z, u1.w};
#pragma unroll
            for (int e = 0; e < 8; ++e) {
                KVs[(sc0 + 2 * e + 0) * LSTR + sr] = bf2f((unsigned short)(w[e] & 0xffffu));
                KVs[(sc0 + 2 * e + 1) * LSTR + sr] = bf2f((unsigned short)(w[e] >> 16));
            }
        }
        __syncthreads();

        float s[4][4] = {};
        for (int d = 0; d < 64; ++d) {
            float4 a4 = *reinterpret_cast<const float4*>(&Qs[d * LSTR + qg * 4]);
            float4 b4 = *reinterpret_cast<const float4*>(&KVs[d * LSTR + kg * 4]);
            float a[4] = {a4.x, a4.y, a4.z, a4.w};
            float bb[4] = {b4.x, b4.y, b4.z, b4.w};
#pragma unroll
            for (int i = 0; i < 4; ++i)
#pragma unroll
                for (int j = 0; j < 4; ++j)
                    s[i][j] = fmaf(a[i], bb[j], s[i][j]);
        }

        int kbase = k0 + kg * 4;
        int tk[4];
#pragma unroll
        for (int j = 0; j < 4; ++j) tk[j] = kv_tok[b * Sk + kbase + j];
#pragma unroll
        for (int i = 0; i < 4; ++i) {
            int qrow = q0 + qg * 4 + i;
#pragma unroll
            for (int j = 0; j < 4; ++j) {
                bool masked = (causal && (kbase + j > qrow)) || (tk[j] == 0);
                s[i][j] = masked ? -INFINITY : s[i][j] * 0.125f;
            }
        }

#pragma unroll
        for (int i = 0; i < 4; ++i) {
            float tm = fmaxf(fmaxf(s[i][0], s[i][1]), fmaxf(s[i][2], s[i][3]));
            tm = fmaxf(tm, __shfl_xor(tm, 1, 16));
            tm = fmaxf(tm, __shfl_xor(tm, 2, 16));
            tm = fmaxf(tm, __shfl_xor(tm, 4, 16));
            tm = fmaxf(tm, __shfl_xor(tm, 8, 16));
            float mnew = fmaxf(m[i], tm);
            float alpha = (mnew == -INFINITY) ? 1.0f : __expf(m[i] - mnew);
            float p[4];
#pragma unroll
            for (int j = 0; j < 4; ++j)
                p[j] = (s[i][j] == -INFINITY) ? 0.0f : __expf(s[i][j] - mnew);
            float4 p4; p4.x = p[0]; p4.y = p[1]; p4.z = p[2]; p4.w = p[3];
            *reinterpret_cast<float4*>(&Ps[(qg * 4 + i) * LSTR + kg * 4]) = p4;
            float rs = p[0] + p[1] + p[2] + p[3];
            rs += __shfl_xor(rs, 1, 16);
            rs += __shfl_xor(rs, 2, 16);
            rs += __shfl_xor(rs, 4, 16);
            rs += __shfl_xor(rs, 8, 16);
            l[i] = l[i] * alpha + rs;
            m[i] = mnew;
#pragma unroll
            for (int j = 0; j < 4; ++j) o[i][j] *= alpha;
        }
        __syncthreads();

        {   // stage V natural [k][d] (cols 1024..1535)
            const unsigned short* p = QKV + (size_t)(b * Sk + k0 + sr) * QSTR + 1024 + h * DH_ + sc0;
            uint4 u0 = *reinterpret_cast<const uint4*>(p);
            uint4 u1 = *reinterpret_cast<const uint4*>(p + 8);
            unsigned int w[8] = {u0.x, u0.y, u0.z, u0.w, u1.x, u1.y, u1.z, u1.w};
#pragma unroll
            for (int e = 0; e < 8; ++e) {
                KVs[sr * LSTR + sc0 + 2 * e + 0] = bf2f((unsigned short)(w[e] & 0xffffu));
                KVs[sr * LSTR + sc0 + 2 * e + 1] = bf2f((unsigned short)(w[e] >> 16));
            }
        }
        __syncthreads();

        for (int k = 0; k < 64; ++k) {
            float4 v4 = *reinterpret_cast<const float4*>(&KVs[k * LSTR + kg * 4]);
            float vv[4] = {v4.x, v4.y, v4.z, v4.w};
            float p0 = Ps[(qg * 4 + 0) * LSTR + k];
            float p1 = Ps[(qg * 4 + 1) * LSTR + k];
            float p2 = Ps[(qg * 4 + 2) * LSTR + k];
            float p3 = Ps[(qg * 4 + 3) * LSTR + k];
#pragma unroll
            for (int j = 0; j < 4; ++j) {
                o[0][j] = fmaf(p0, vv[j], o[0][j]);
                o[1][j] = fmaf(p1, vv[j], o[1][j]);
                o[2][j] = fmaf(p2, vv[j], o[2][j]);
                o[3][j] = fmaf(p3, vv[j], o[3][j]);
            }
        }
    }

#pragma unroll
    for (int i = 0; i < 4; ++i) {
        float inv = (l[i] > 0.0f) ? 1.0f / l[i] : 0.0f;
        ushort4 r;
        r.x = f2bf(o[i][0] * inv); r.y = f2bf(o[i][1] * inv);
        r.z = f2bf(o[i][2] * inv); r.w = f2bf(o[i][3] * inv);
        *reinterpret_cast<ushort4*>(
            &O[(size_t)(b * 512 + q0 + qg * 4 + i) * D_ + h * DH_ + kg * 4]) = r;
    }
}

// ---------------- residual add + LayerNorm: f32 stream + bf16 shadow ----------------
__global__ __launch_bounds__(256) void add_ln_kernel(float* __restrict__ X,
        unsigned short* __restrict__ Xb,
        const float* __restrict__ R, const void* __restrict__ ln, size_t goff,
        const int* __restrict__ flagp)
{
    const int mode = flagp[0];
    __shared__ float red[256];
    int row = blockIdx.x, tid = threadIdx.x;
    size_t base = (size_t)row * D_;
    float v0 = X[base + tid] + R[base + tid];
    float v1 = X[base + 256 + tid] + R[base + 256 + tid];
    red[tid] = v0 + v1; __syncthreads();
    for (int o = 128; o > 0; o >>= 1) {
        if (tid < o) red[tid] += red[tid + o];
        __syncthreads();
    }
    float mu = red[0] * (1.0f / (float)D_);
    __syncthreads();
    float d0 = v0 - mu, d1 = v1 - mu;
    red[tid] = d0 * d0 + d1 * d1; __syncthreads();
    for (int o = 128; o > 0; o >>= 1) {
        if (tid < o) red[tid] += red[tid + o];
        __syncthreads();
    }
    float inv = rsqrtf(red[0] * (1.0f / (float)D_) + 1e-5f);
    float r0 = d0 * inv * ldp(ln, goff + tid, mode)       + ldp(ln, goff + D_ + tid, mode);
    float r1 = d1 * inv * ldp(ln, goff + 256 + tid, mode) + ldp(ln, goff + D_ + 256 + tid, mode);
    X[base + tid] = r0;         Xb[base + tid] = f2bf(r0);
    X[base + 256 + tid] = r1;   Xb[base + 256 + tid] = f2bf(r1);
}

// ---------------- f32 -> output (bf16 or f32 per mode) ----------------
__global__ __launch_bounds__(256) void to_out_kernel(const float* __restrict__ in,
        void* __restrict__ out, int n, const int* __restrict__ flagp)
{
    const int mode = flagp[0];
    int i = blockIdx.x * 256 + threadIdx.x;
    if (i < n) {
        float v = in[i];
        if (mode) ((float*)out)[i] = v;
        else      ((__hip_bfloat16*)out)[i] = __float2bfloat16(v);
    }
}

extern "C" void kernel_launch(void* const* d_in, const int* in_sizes, int n_in,
                              void* d_out, int out_size, void* d_ws, size_t ws_size,
                              hipStream_t stream) {
    const int* tin  = (const int*)d_in[0];
    const int* tout = (const int*)d_in[1];
    const void* emi = d_in[2];
    const void* emo = d_in[3];
    const void* eaw = d_in[4];
    const void* eab = d_in[5];
    const void* eln = d_in[6];
    const void* ew1 = d_in[7];
    const void* eb1 = d_in[8];
    const void* ew2 = d_in[9];
    const void* eb2 = d_in[10];
    const void* dsw = d_in[11];
    const void* dsb = d_in[12];
    const void* dcw = d_in[13];
    const void* dcb = d_in[14];
    const void* dln = d_in[15];
    const void* dw1 = d_in[16];
    const void* db1 = d_in[17];
    const void* dw2 = d_in[18];
    const void* db2 = d_in[19];

    // ws (~48 MB): flag | X,Y,P f32 | Xb,Yb bf16 | QKV(3MD)+CTX(MD) bf16 (HB overlays)
    int*   flagp = (int*)d_ws;
    float* X = (float*)d_ws + 64;
    float* Y = X + MD_;
    float* P = Y + MD_;
    unsigned short* Xb   = (unsigned short*)(P + MD_);
    unsigned short* Yb   = Xb + MD_;
    unsigned short* QKVb = Yb + MD_;
    unsigned short* CTXb = QKVb + 3 * (size_t)MD_;
    unsigned short* HB   = QKVb;   // [M_, 2048] overlays QKV+CTX during FFN

    const size_t WDD = (size_t)D_ * D_;
    const int AGRID = B_ * NH_ * 8;

    auto g4 = [&](const unsigned short* A, int K, const void* W, size_t woff, int nsub,
                  const void* bias, size_t boff, void* C, int ldc, int N, int cmode, int relu) {
        mfma_gemm<4><<<dim3(N / 128, M_ / 128), 256, 0, stream>>>(
            A, K, W, woff, nsub, bias, boff, C, ldc, cmode, relu, flagp);
    };
    auto g2 = [&](const unsigned short* A, int K, const void* W, size_t woff, int nsub,
                  const void* bias, size_t boff, void* C, int ldc, int N, int cmode, int relu) {
        mfma_gemm<2><<<dim3(N / 128, M_ / 64), 256, 0, stream>>>(
            A, K, W, woff, nsub, bias, boff, C, ldc, cmode, relu, flagp);
    };

    detect_kernel<<<1, 256, 0, stream>>>(emi, flagp);
    embed_pe_kernel<<<(M_ * D_) / 256, 256, 0, stream>>>(tin, emi, X, Xb, flagp);
    embed_pe_kernel<<<(M_ * D_) / 256, 256, 0, stream>>>(tout, emo, Y, Yb, flagp);

    // ---- encoder ----
    for (int l = 0; l < L_; ++l) {
        size_t w = (size_t)l * 4 * WDD, bb = (size_t)l * 4 * D_;
        g4(Xb, D_, eaw, w, 512, eab, bb, QKVb, QSTR, 1536, 1, 0);           // fused QKV
        fattn_kernel<<<AGRID, 256, 0, stream>>>(QKVb, tin, CTXb, S_, 0);
        g2(CTXb, D_, eaw, w + 3 * WDD, 512, eab, bb + 3 * D_, P, D_, 512, 0, 0);
        add_ln_kernel<<<M_, 256, 0, stream>>>(X, Xb, P, eln, ((size_t)l * 2 + 0) * 2 * D_, flagp);
        g4(Xb, D_, ew1, (size_t)l * D_ * HID_, 2048, eb1, (size_t)l * HID_, HB, HID_, 2048, 1, 1);
        g2(HB, HID_, ew2, (size_t)l * HID_ * D_, 512, eb2, (size_t)l * D_, P, D_, 512, 0, 0);
        add_ln_kernel<<<M_, 256, 0, stream>>>(X, Xb, P, eln, ((size_t)l * 2 + 1) * 2 * D_, flagp);
    }

    // ---- decoder ----
    for (int l = 0; l < L_; ++l) {
        size_t w = (size_t)l * 4 * WDD, bb = (size_t)l * 4 * D_;
        // self-attention (causal)
        g4(Yb, D_, dsw, w, 512, dsb, bb, QKVb, QSTR, 1536, 1, 0);
        fattn_kernel<<<AGRID, 256, 0, stream>>>(QKVb, tout, CTXb, T_, 1);
        g2(CTXb, D_, dsw, w + 3 * WDD, 512, dsb, bb + 3 * D_, P, D_, 512, 0, 0);
        add_ln_kernel<<<M_, 256, 0, stream>>>(Y, Yb, P, dln, ((size_t)l * 3 + 0) * 2 * D_, flagp);
        // cross-attention: Q from Y, K/V from X
        g2(Yb, D_, dcw, w, 512, dcb, bb, QKVb, QSTR, 512, 1, 0);            // Q -> cols 0..511
        g4(Xb, D_, dcw, w + WDD, 512, dcb, bb + D_, QKVb + 512, QSTR, 1024, 1, 0); // K,V
        fattn_kernel<<<AGRID, 256, 0, stream>>>(QKVb, tin, CTXb, S_, 0);
        g2(CTXb, D_, dcw, w + 3 * WDD, 512, dcb, bb + 3 * D_, P, D_, 512, 0, 0);
        add_ln_kernel<<<M_, 256, 0, stream>>>(Y, Yb, P, dln, ((size_t)l * 3 + 1) * 2 * D_, flagp);
        // FFN
        g4(Yb, D_, dw1, (size_t)l * D_ * HID_, 2048, db1, (size_t)l * HID_, HB, HID_, 2048, 1, 1);
        g2(HB, HID_, dw2, (size_t)l * HID_ * D_, 512, db2, (size_t)l * D_, P, D_, 512, 0, 0);
        add_ln_kernel<<<M_, 256, 0, stream>>>(Y, Yb, P, dln, ((size_t)l * 3 + 2) * 2 * D_, flagp);
    }

    to_out_kernel<<<(out_size + 255) / 256, 256, 0, stream>>>(Y, d_out, out_size, flagp);
}